// Round 6
// baseline (260.810 us; speedup 1.0000x reference)
//
#include <hip/hip_runtime.h>
#include <math.h>

#define N_NODES 50000
#define N_EDGES 800000
#define EPS 1e-7f
#define NEG_SLOPE 0.01f

#define SCAN_B 1024
#define SCAN_GRID ((N_NODES + SCAN_B - 1) / SCAN_B)  // 49

typedef __attribute__((ext_vector_type(8))) short short8;
typedef __attribute__((ext_vector_type(4))) float f32x4;

// round-to-nearest-even bf16 (low 16 bits of result)
__device__ __forceinline__ unsigned bf16_rne(float x) {
    unsigned u = __float_as_uint(x);
    u += 0x7fffu + ((u >> 16) & 1u);
    return u >> 16;
}
__device__ __forceinline__ unsigned pack_bf16(float a, float b) {
    return bf16_rne(a) | (bf16_rne(b) << 16);
}

// ---------------- CSR build ----------------

// hist + (one extra block) weight packing fused into one dispatch
__global__ __launch_bounds__(256) void hist_pack_kernel(
    const int* __restrict__ dst, int* __restrict__ cnt,
    const float* __restrict__ W_neigh, const float* __restrict__ W_self,
    const float* __restrict__ b_neigh, const float* __restrict__ bias,
    unsigned* __restrict__ wnp, unsigned* __restrict__ wsp, float* __restrict__ bb)
{
    if (blockIdx.x == N_EDGES / 256) {  // pack block
        const int t = threadIdx.x;
        const float2* Wn2 = (const float2*)W_neigh;
        const float2* Ws2 = (const float2*)W_self;
        for (int i = t; i < 64 * 128; i += 256) {
            float2 v = Wn2[i];
            wnp[i] = pack_bf16(v.x, v.y);
        }
        for (int i = t; i < 64 * 32; i += 256) {
            float2 v = Ws2[i];
            wsp[i] = pack_bf16(v.x, v.y);
        }
        if (t < 64) bb[t] = b_neigh[t] + bias[t];
        return;
    }
    const int i = blockIdx.x * 256 + threadIdx.x;  // 3125*256 == 800000 exact
    atomicAdd(&cnt[dst[i]], 1);
}

__global__ __launch_bounds__(SCAN_B) void block_reduce_kernel(const int* __restrict__ cnt,
                                                              int* __restrict__ bsum) {
    __shared__ int sd[SCAN_B];
    const int t = threadIdx.x;
    const int i = blockIdx.x * SCAN_B + t;
    sd[t] = (i < N_NODES) ? cnt[i] : 0;
    __syncthreads();
    for (int st = SCAN_B / 2; st > 0; st >>= 1) {
        if (t < st) sd[t] += sd[t + st];
        __syncthreads();
    }
    if (t == 0) bsum[blockIdx.x] = sd[0];
}

__global__ __launch_bounds__(64) void scan_bsums_kernel(const int* __restrict__ bsum,
                                                        int* __restrict__ bofs) {
    const int lane = threadIdx.x;
    int orig = (lane < SCAN_GRID) ? bsum[lane] : 0;
    int v = orig;
    for (int d = 1; d < 64; d <<= 1) {
        int u = __shfl_up(v, d, 64);
        if (lane >= d) v += u;
    }
    if (lane < SCAN_GRID) bofs[lane] = v - orig;  // exclusive
}

__global__ __launch_bounds__(SCAN_B) void scan_write_kernel(const int* __restrict__ cnt,
                                                            const int* __restrict__ bofs,
                                                            int* __restrict__ off,
                                                            int* __restrict__ cursor) {
    __shared__ int sd[SCAN_B];
    const int t = threadIdx.x;
    const int i = blockIdx.x * SCAN_B + t;
    const int v = (i < N_NODES) ? cnt[i] : 0;
    sd[t] = v;
    __syncthreads();
    for (int st = 1; st < SCAN_B; st <<= 1) {
        int u = (t >= st) ? sd[t - st] : 0;
        __syncthreads();
        sd[t] += u;
        __syncthreads();
    }
    const int excl = sd[t] - v + bofs[blockIdx.x];
    if (i < N_NODES) {
        off[i] = excl;
        cursor[i] = excl;
    }
    if (i == N_NODES - 1) off[N_NODES] = excl + v;  // == N_EDGES
}

// scatter + per-edge geometry: one 8-byte record per edge in dst-sorted order
//   u.x = bf16(wx) | bf16(wy)<<16 ; u.y = bf16(wz) | src<<16  (src < 65536)
__global__ __launch_bounds__(256) void scatter_geom_kernel(
    const int* __restrict__ src, const int* __restrict__ dst,
    const float* __restrict__ pos, int* __restrict__ cursor,
    uint2* __restrict__ gdata)
{
    const int i = blockIdx.x * 256 + threadIdx.x;  // 3125*256 == 800000 exact
    const int s = src[i], d = dst[i];
    const float sx = pos[s * 3 + 0], sy = pos[s * 3 + 1], sz = pos[s * 3 + 2];
    const float dx = pos[d * 3 + 0], dy = pos[d * 3 + 1], dz = pos[d * 3 + 2];
    const float rx = dx - sx, ry = dy - sy, rz = dz - sz;
    const float inv =
        __builtin_amdgcn_rcpf(__builtin_amdgcn_sqrtf(rx * rx + ry * ry + rz * rz) + EPS);
    const float wx = (rx + 1.f) * inv;
    const float wy = (ry + 1.f) * inv;
    const float wz = (rz + 1.f) * inv;
    const int p = atomicAdd(&cursor[d], 1);
    gdata[p] = make_uint2(pack_bf16(wx, wy), bf16_rne(wz) | ((unsigned)s << 16));
}

// ---------------- aggregation: wave=node, no LDS, no barriers ----------------
// Edge records are wave-uniform -> scalar loads + SALU decode; only the MLP math
// and the feat gather are vector work. Depth-2 software pipeline hides latency.

__global__ __launch_bounds__(256) void aggregate_kernel(
    const float* __restrict__ feat, const float* __restrict__ W_sp,
    const float* __restrict__ b_sp, const int* __restrict__ off,
    const uint2* __restrict__ gdata, unsigned int* __restrict__ accp /* [N][128] */)
{
    const int lane = threadIdx.x & 63;
    const int w = threadIdx.x >> 6;
    const int n = (blockIdx.x << 2) + w;  // 12500*4 == 50000 exact

    // per-lane spatial-MLP rows: lane = feature i, handles j = lane*4+h
    float wsp0[4], wsp1[4], wsp2[4], bsp[4];
#pragma unroll
    for (int h = 0; h < 4; ++h) {
        int j = lane * 4 + h;
        wsp0[h] = W_sp[j * 3 + 0];
        wsp1[h] = W_sp[j * 3 + 1];
        wsp2[h] = W_sp[j * 3 + 2];
        bsp[h]  = b_sp[j];
    }

    const int beg = __builtin_amdgcn_readfirstlane(off[n]);
    const int end = __builtin_amdgcn_readfirstlane(off[n + 1]);
    const int deg = end - beg;
    const uint2* gp = gdata + beg;

    float a0 = 0.f, a1 = 0.f, a2 = 0.f, a3 = 0.f;

    if (deg > 0) {
        const int dm = deg - 1;
        uint2 u0 = gp[0];
        uint2 u1 = gp[min(1, dm)];
        float f0 = feat[(size_t)(u0.y >> 16) * 64 + lane];

        for (int e = 0; e < deg; ++e) {
            // prefetch: g two ahead, feat one ahead (breaks g->feat chain)
            uint2 u2 = gp[min(e + 2, dm)];
            float f1 = feat[(size_t)(u1.y >> 16) * 64 + lane];

            const float wx = __uint_as_float(u0.x << 16);
            const float wy = __uint_as_float(u0.x & 0xffff0000u);
            const float wz = __uint_as_float(u0.y << 16);

            float t0 = fmaf(wx, wsp0[0], fmaf(wy, wsp1[0], fmaf(wz, wsp2[0], bsp[0])));
            float t1 = fmaf(wx, wsp0[1], fmaf(wy, wsp1[1], fmaf(wz, wsp2[1], bsp[1])));
            float t2 = fmaf(wx, wsp0[2], fmaf(wy, wsp1[2], fmaf(wz, wsp2[2], bsp[2])));
            float t3 = fmaf(wx, wsp0[3], fmaf(wy, wsp1[3], fmaf(wz, wsp2[3], bsp[3])));
            // leakyrelu(t) == max(t, 0.01t) for slope < 1
            a0 = fmaf(fmaxf(t0, t0 * NEG_SLOPE), f0, a0);
            a1 = fmaf(fmaxf(t1, t1 * NEG_SLOPE), f0, a1);
            a2 = fmaf(fmaxf(t2, t2 * NEG_SLOPE), f0, a2);
            a3 = fmaf(fmaxf(t3, t3 * NEG_SLOPE), f0, a3);

            u0 = u1; u1 = u2; f0 = f1;
        }
    }

    const float mscale = 1.f / fmaxf((float)deg, 1.f);
    a0 *= mscale; a1 *= mscale; a2 *= mscale; a3 *= mscale;
    uint2 pv = make_uint2(pack_bf16(a0, a1), pack_bf16(a2, a3));
    *reinterpret_cast<uint2*>(&accp[(size_t)n * 128 + lane * 2]) = pv;
}

// ---------------- projection via MFMA ----------------

__device__ __forceinline__ short8 feat_frag_bf16(const float* p) {
    float4 x0 = *reinterpret_cast<const float4*>(p);
    float4 x1 = *reinterpret_cast<const float4*>(p + 4);
    union { unsigned u[4]; short8 s; } c;
    c.u[0] = pack_bf16(x0.x, x0.y);
    c.u[1] = pack_bf16(x0.z, x0.w);
    c.u[2] = pack_bf16(x1.x, x1.y);
    c.u[3] = pack_bf16(x1.z, x1.w);
    return c.s;
}

__global__ __launch_bounds__(256) void project_mfma_kernel(
    const float* __restrict__ feat, const short* __restrict__ accb,
    const short* __restrict__ wnb, const short* __restrict__ wsb,
    const float* __restrict__ bb, float* __restrict__ out)
{
    const int lane = threadIdx.x & 63;
    const int ct = threadIdx.x >> 6;
    const int nodeBase = blockIdx.x * 16;   // 3125*16 == 50000 exact
    const int mrow = lane & 15;
    const int quad = lane >> 4;
    const int o = ct * 16 + mrow;

    f32x4 acc = {0.f, 0.f, 0.f, 0.f};

    const short* Ar = accb + (size_t)(nodeBase + mrow) * 256 + quad * 8;
    const short* Br = wnb + o * 256 + quad * 8;
#pragma unroll
    for (int ks = 0; ks < 8; ++ks) {
        short8 a = *reinterpret_cast<const short8*>(Ar + ks * 32);
        short8 b = *reinterpret_cast<const short8*>(Br + ks * 32);
        acc = __builtin_amdgcn_mfma_f32_16x16x32_bf16(a, b, acc, 0, 0, 0);
    }

    const float* Fr = feat + (size_t)(nodeBase + mrow) * 64 + quad * 8;
    const short* Sr = wsb + o * 64 + quad * 8;
#pragma unroll
    for (int ks = 0; ks < 2; ++ks) {
        short8 a = feat_frag_bf16(Fr + ks * 32);
        short8 b = *reinterpret_cast<const short8*>(Sr + ks * 32);
        acc = __builtin_amdgcn_mfma_f32_16x16x32_bf16(a, b, acc, 0, 0, 0);
    }

    const float badd = bb[o];
#pragma unroll
    for (int r = 0; r < 4; ++r) {
        out[(size_t)(nodeBase + quad * 4 + r) * 64 + o] = acc[r] + badd;
    }
}

// ---------------- launch ----------------

extern "C" void kernel_launch(void* const* d_in, const int* in_sizes, int n_in,
                              void* d_out, int out_size, void* d_ws, size_t ws_size,
                              hipStream_t stream) {
    (void)in_sizes; (void)n_in; (void)out_size; (void)ws_size;
    const float* feat    = (const float*)d_in[0];
    const float* pos     = (const float*)d_in[1];
    const int*   src     = (const int*)d_in[2];
    const int*   dst     = (const int*)d_in[3];
    const float* W_self  = (const float*)d_in[4];
    const float* W_sp    = (const float*)d_in[5];
    const float* b_sp    = (const float*)d_in[6];
    const float* W_neigh = (const float*)d_in[7];
    const float* b_neigh = (const float*)d_in[8];
    const float* bias    = (const float*)d_in[9];
    float* out = (float*)d_out;

    // ws layout: gdata[E] uint2 (8B aligned at base) | accp[N*128] uint |
    //            wnp[8192] | wsp[2048] | bb[64]f | cnt[N] | off[N+1] | cursor[N] | bsum | bofs
    uint2*        gdata = (uint2*)d_ws;
    unsigned int* accp  = (unsigned int*)(gdata + N_EDGES);
    unsigned int* wnp   = accp + (size_t)N_NODES * 128;
    unsigned int* wsp   = wnp + 8192;
    float*        bb    = (float*)(wsp + 2048);
    int* cnt    = (int*)(bb + 64);
    int* off    = cnt + N_NODES;
    int* cursor = off + N_NODES + 1;
    int* bsum   = cursor + N_NODES;
    int* bofs   = bsum + SCAN_GRID;

    hipMemsetAsync(cnt, 0, N_NODES * sizeof(int), stream);
    hist_pack_kernel<<<N_EDGES / 256 + 1, 256, 0, stream>>>(dst, cnt, W_neigh, W_self,
                                                            b_neigh, bias, wnp, wsp, bb);
    block_reduce_kernel<<<SCAN_GRID, SCAN_B, 0, stream>>>(cnt, bsum);
    scan_bsums_kernel<<<1, 64, 0, stream>>>(bsum, bofs);
    scan_write_kernel<<<SCAN_GRID, SCAN_B, 0, stream>>>(cnt, bofs, off, cursor);
    scatter_geom_kernel<<<N_EDGES / 256, 256, 0, stream>>>(src, dst, pos, cursor, gdata);
    aggregate_kernel<<<N_NODES / 4, 256, 0, stream>>>(feat, W_sp, b_sp, off, gdata, accp);
    project_mfma_kernel<<<N_NODES / 16, 256, 0, stream>>>(feat, (const short*)accp,
                                                          (const short*)wnp, (const short*)wsp,
                                                          bb, out);
}

// Round 7
// 194.271 us; speedup vs baseline: 1.3425x; 1.3425x over previous
//
#include <hip/hip_runtime.h>
#include <math.h>

#define N_NODES 50000
#define N_EDGES 800000
#define EPS 1e-7f
#define NEG_SLOPE 0.01f

#define SCAN_B 1024
#define SCAN_GRID ((N_NODES + SCAN_B - 1) / SCAN_B)  // 49

typedef __attribute__((ext_vector_type(8))) short short8;
typedef __attribute__((ext_vector_type(4))) float f32x4;

// round-to-nearest-even bf16 (low 16 bits of result)
__device__ __forceinline__ unsigned bf16_rne(float x) {
    unsigned u = __float_as_uint(x);
    u += 0x7fffu + ((u >> 16) & 1u);
    return u >> 16;
}
__device__ __forceinline__ unsigned pack_bf16(float a, float b) {
    return bf16_rne(a) | (bf16_rne(b) << 16);
}

// ---------------- pass 1: hist + per-edge geometry (edge order) + weight pack ----------------
// grec[i]: u.x = bf16(wx)|bf16(wy)<<16 ; u.y = bf16(wz)|src<<16   (src < 65536)

__global__ __launch_bounds__(256) void hist_geom_kernel(
    const int* __restrict__ src, const int* __restrict__ dst,
    const float* __restrict__ pos, int* __restrict__ cnt,
    int* __restrict__ slot, uint2* __restrict__ grec,
    const float* __restrict__ W_neigh, const float* __restrict__ W_self,
    const float* __restrict__ b_neigh, const float* __restrict__ bias,
    unsigned* __restrict__ wnp, unsigned* __restrict__ wsp, float* __restrict__ bb)
{
    if (blockIdx.x == N_EDGES / 256) {  // weight-pack block
        const int t = threadIdx.x;
        const float2* Wn2 = (const float2*)W_neigh;
        const float2* Ws2 = (const float2*)W_self;
        for (int i = t; i < 64 * 128; i += 256) {
            float2 v = Wn2[i];
            wnp[i] = pack_bf16(v.x, v.y);
        }
        for (int i = t; i < 64 * 32; i += 256) {
            float2 v = Ws2[i];
            wsp[i] = pack_bf16(v.x, v.y);
        }
        if (t < 64) bb[t] = b_neigh[t] + bias[t];
        return;
    }
    const int i = blockIdx.x * 256 + threadIdx.x;  // 3125*256 == 800000 exact
    const int s = src[i], d = dst[i];
    const float sx = pos[s * 3 + 0], sy = pos[s * 3 + 1], sz = pos[s * 3 + 2];
    const float dx = pos[d * 3 + 0], dy = pos[d * 3 + 1], dz = pos[d * 3 + 2];
    const float rx = dx - sx, ry = dy - sy, rz = dz - sz;
    const float inv =
        __builtin_amdgcn_rcpf(__builtin_amdgcn_sqrtf(rx * rx + ry * ry + rz * rz) + EPS);
    grec[i] = make_uint2(pack_bf16((rx + 1.f) * inv, (ry + 1.f) * inv),
                         bf16_rne((rz + 1.f) * inv) | ((unsigned)s << 16));
    slot[i] = atomicAdd(&cnt[d], 1);
}

// ---------------- scan (3 small kernels) ----------------

__global__ __launch_bounds__(SCAN_B) void block_reduce_kernel(const int* __restrict__ cnt,
                                                              int* __restrict__ bsum) {
    __shared__ int sd[SCAN_B];
    const int t = threadIdx.x;
    const int i = blockIdx.x * SCAN_B + t;
    sd[t] = (i < N_NODES) ? cnt[i] : 0;
    __syncthreads();
    for (int st = SCAN_B / 2; st > 0; st >>= 1) {
        if (t < st) sd[t] += sd[t + st];
        __syncthreads();
    }
    if (t == 0) bsum[blockIdx.x] = sd[0];
}

__global__ __launch_bounds__(64) void scan_bsums_kernel(const int* __restrict__ bsum,
                                                        int* __restrict__ bofs) {
    const int lane = threadIdx.x;
    int orig = (lane < SCAN_GRID) ? bsum[lane] : 0;
    int v = orig;
    for (int d = 1; d < 64; d <<= 1) {
        int u = __shfl_up(v, d, 64);
        if (lane >= d) v += u;
    }
    if (lane < SCAN_GRID) bofs[lane] = v - orig;  // exclusive
}

__global__ __launch_bounds__(SCAN_B) void scan_write_kernel(const int* __restrict__ cnt,
                                                            const int* __restrict__ bofs,
                                                            int* __restrict__ off) {
    __shared__ int sd[SCAN_B];
    const int t = threadIdx.x;
    const int i = blockIdx.x * SCAN_B + t;
    const int v = (i < N_NODES) ? cnt[i] : 0;
    sd[t] = v;
    __syncthreads();
    for (int st = 1; st < SCAN_B; st <<= 1) {
        int u = (t >= st) ? sd[t - st] : 0;
        __syncthreads();
        sd[t] += u;
        __syncthreads();
    }
    const int excl = sd[t] - v + bofs[blockIdx.x];
    if (i < N_NODES) off[i] = excl;
    if (i == N_NODES - 1) off[N_NODES] = excl + v;  // == N_EDGES
}

// ---------------- pass 2: pure permute (no atomics, no gathers) ----------------

__global__ __launch_bounds__(256) void scatter_kernel(
    const uint2* __restrict__ grec, const int* __restrict__ dst,
    const int* __restrict__ off, const int* __restrict__ slot,
    uint2* __restrict__ gdata)
{
    const int i = blockIdx.x * 256 + threadIdx.x;  // 3125*256 == 800000 exact
    gdata[off[dst[i]] + slot[i]] = grec[i];
}

// ---------------- pass 3: fused aggregation + MFMA projection ----------------
// Block = 4 waves = 16 nodes. Wave w aggregates nodes nb+4w..nb+4w+3 (streaming,
// no barriers inside), packs bf16 rows to LDS, then computes its 16-col MFMA tile.

#define ACC_STRIDE 264  // bf16 elements per LDS row (256 + 8 pad; keeps 16B align)

__device__ __forceinline__ short8 feat_frag_bf16(const float* p) {
    float4 x0 = *reinterpret_cast<const float4*>(p);
    float4 x1 = *reinterpret_cast<const float4*>(p + 4);
    union { unsigned u[4]; short8 s; } c;
    c.u[0] = pack_bf16(x0.x, x0.y);
    c.u[1] = pack_bf16(x0.z, x0.w);
    c.u[2] = pack_bf16(x1.x, x1.y);
    c.u[3] = pack_bf16(x1.z, x1.w);
    return c.s;
}

__global__ __launch_bounds__(256) void aggregate_project_kernel(
    const float* __restrict__ feat, const float* __restrict__ W_sp,
    const float* __restrict__ b_sp, const int* __restrict__ off,
    const uint2* __restrict__ gdata, const short* __restrict__ wnb,
    const short* __restrict__ wsb, const float* __restrict__ bb,
    float* __restrict__ out)
{
    __shared__ unsigned short accS[16 * ACC_STRIDE];  // 8448 B

    const int lane = threadIdx.x & 63;
    const int w = threadIdx.x >> 6;
    const int nb = blockIdx.x << 4;  // 3125*16 == 50000 exact

    // per-lane spatial-MLP rows: lane = feature i, handles j = lane*4+h
    float wsp0[4], wsp1[4], wsp2[4], bsp[4];
#pragma unroll
    for (int h = 0; h < 4; ++h) {
        int j = lane * 4 + h;
        wsp0[h] = W_sp[j * 3 + 0];
        wsp1[h] = W_sp[j * 3 + 1];
        wsp2[h] = W_sp[j * 3 + 2];
        bsp[h]  = b_sp[j];
    }

    // ---- aggregation: wave w handles rows 4w..4w+3, one node at a time ----
    for (int q = 0; q < 4; ++q) {
        const int r = (w << 2) + q;
        const int n = nb + r;
        const int beg = __builtin_amdgcn_readfirstlane(off[n]);
        const int end = __builtin_amdgcn_readfirstlane(off[n + 1]);
        const int deg = end - beg;
        const uint2* gp = gdata + beg;

        float a0 = 0.f, a1 = 0.f, a2 = 0.f, a3 = 0.f;

        if (deg > 0) {
            const int dm = deg - 1;
            // records 4 ahead, feats 2 ahead: 2 VMEM in flight, full-iter cover
            uint2 u0 = gp[0];
            uint2 u1 = gp[min(1, dm)];
            uint2 u2 = gp[min(2, dm)];
            uint2 u3 = gp[min(3, dm)];
            float f0 = feat[(size_t)(u0.y >> 16) * 64 + lane];
            float f1 = feat[(size_t)(u1.y >> 16) * 64 + lane];

            for (int e = 0; e < deg; e += 2) {
                uint2 u4 = gp[min(e + 4, dm)];
                uint2 u5 = gp[min(e + 5, dm)];
                float f2 = feat[(size_t)(u2.y >> 16) * 64 + lane];
                float f3 = feat[(size_t)(u3.y >> 16) * 64 + lane];

                {
                    const float wx = __uint_as_float(u0.x << 16);
                    const float wy = __uint_as_float(u0.x & 0xffff0000u);
                    const float wz = __uint_as_float(u0.y << 16);
                    float t0 = fmaf(wx, wsp0[0], fmaf(wy, wsp1[0], fmaf(wz, wsp2[0], bsp[0])));
                    float t1 = fmaf(wx, wsp0[1], fmaf(wy, wsp1[1], fmaf(wz, wsp2[1], bsp[1])));
                    float t2 = fmaf(wx, wsp0[2], fmaf(wy, wsp1[2], fmaf(wz, wsp2[2], bsp[2])));
                    float t3 = fmaf(wx, wsp0[3], fmaf(wy, wsp1[3], fmaf(wz, wsp2[3], bsp[3])));
                    a0 = fmaf(fmaxf(t0, t0 * NEG_SLOPE), f0, a0);
                    a1 = fmaf(fmaxf(t1, t1 * NEG_SLOPE), f0, a1);
                    a2 = fmaf(fmaxf(t2, t2 * NEG_SLOPE), f0, a2);
                    a3 = fmaf(fmaxf(t3, t3 * NEG_SLOPE), f0, a3);
                }
                {
                    const float m1 = (e + 1 <= dm) ? 1.f : 0.f;
                    const float fm = f1 * m1;
                    const float wx = __uint_as_float(u1.x << 16);
                    const float wy = __uint_as_float(u1.x & 0xffff0000u);
                    const float wz = __uint_as_float(u1.y << 16);
                    float t0 = fmaf(wx, wsp0[0], fmaf(wy, wsp1[0], fmaf(wz, wsp2[0], bsp[0])));
                    float t1 = fmaf(wx, wsp0[1], fmaf(wy, wsp1[1], fmaf(wz, wsp2[1], bsp[1])));
                    float t2 = fmaf(wx, wsp0[2], fmaf(wy, wsp1[2], fmaf(wz, wsp2[2], bsp[2])));
                    float t3 = fmaf(wx, wsp0[3], fmaf(wy, wsp1[3], fmaf(wz, wsp2[3], bsp[3])));
                    a0 = fmaf(fmaxf(t0, t0 * NEG_SLOPE), fm, a0);
                    a1 = fmaf(fmaxf(t1, t1 * NEG_SLOPE), fm, a1);
                    a2 = fmaf(fmaxf(t2, t2 * NEG_SLOPE), fm, a2);
                    a3 = fmaf(fmaxf(t3, t3 * NEG_SLOPE), fm, a3);
                }

                u0 = u2; u1 = u3; u2 = u4; u3 = u5;
                f0 = f2; f1 = f3;
            }
        }

        const float mscale = 1.f / fmaxf((float)deg, 1.f);
        uint2 pv = make_uint2(pack_bf16(a0 * mscale, a1 * mscale),
                              pack_bf16(a2 * mscale, a3 * mscale));
        *reinterpret_cast<uint2*>(&accS[r * ACC_STRIDE + lane * 4]) = pv;
    }
    __syncthreads();

    // ---- projection: wave w -> output col-tile w (cols w*16..w*16+15) ----
    const int mrow = lane & 15;
    const int quad = lane >> 4;
    const int o = (w << 4) + mrow;

    f32x4 acc = {0.f, 0.f, 0.f, 0.f};

    const unsigned short* Ar = &accS[mrow * ACC_STRIDE + quad * 8];
    const short* Br = wnb + o * 256 + quad * 8;
#pragma unroll
    for (int ks = 0; ks < 8; ++ks) {
        short8 a = *reinterpret_cast<const short8*>(Ar + ks * 32);
        short8 b = *reinterpret_cast<const short8*>(Br + ks * 32);
        acc = __builtin_amdgcn_mfma_f32_16x16x32_bf16(a, b, acc, 0, 0, 0);
    }

    const float* Fr = feat + (size_t)(nb + mrow) * 64 + quad * 8;
    const short* Sr = wsb + o * 64 + quad * 8;
#pragma unroll
    for (int ks = 0; ks < 2; ++ks) {
        short8 a = feat_frag_bf16(Fr + ks * 32);
        short8 b = *reinterpret_cast<const short8*>(Sr + ks * 32);
        acc = __builtin_amdgcn_mfma_f32_16x16x32_bf16(a, b, acc, 0, 0, 0);
    }

    const float badd = bb[o];
#pragma unroll
    for (int r = 0; r < 4; ++r) {
        out[(size_t)(nb + quad * 4 + r) * 64 + o] = acc[r] + badd;
    }
}

// ---------------- launch ----------------

extern "C" void kernel_launch(void* const* d_in, const int* in_sizes, int n_in,
                              void* d_out, int out_size, void* d_ws, size_t ws_size,
                              hipStream_t stream) {
    (void)in_sizes; (void)n_in; (void)out_size; (void)ws_size;
    const float* feat    = (const float*)d_in[0];
    const float* pos     = (const float*)d_in[1];
    const int*   src     = (const int*)d_in[2];
    const int*   dst     = (const int*)d_in[3];
    const float* W_self  = (const float*)d_in[4];
    const float* W_sp    = (const float*)d_in[5];
    const float* b_sp    = (const float*)d_in[6];
    const float* W_neigh = (const float*)d_in[7];
    const float* b_neigh = (const float*)d_in[8];
    const float* bias    = (const float*)d_in[9];
    float* out = (float*)d_out;

    // ws layout: grec[E] uint2 | gdata[E] uint2 | slot[E] | wnp[8192] | wsp[2048] |
    //            bb[64]f | cnt[N] | off[N+1] | bsum | bofs
    uint2*        grec  = (uint2*)d_ws;
    uint2*        gdata = grec + N_EDGES;
    int*          slot  = (int*)(gdata + N_EDGES);
    unsigned int* wnp   = (unsigned int*)(slot + N_EDGES);
    unsigned int* wsp   = wnp + 8192;
    float*        bb    = (float*)(wsp + 2048);
    int* cnt  = (int*)(bb + 64);
    int* off  = cnt + N_NODES;
    int* bsum = off + N_NODES + 1;
    int* bofs = bsum + SCAN_GRID;

    hipMemsetAsync(cnt, 0, N_NODES * sizeof(int), stream);
    hist_geom_kernel<<<N_EDGES / 256 + 1, 256, 0, stream>>>(
        src, dst, pos, cnt, slot, grec, W_neigh, W_self, b_neigh, bias, wnp, wsp, bb);
    block_reduce_kernel<<<SCAN_GRID, SCAN_B, 0, stream>>>(cnt, bsum);
    scan_bsums_kernel<<<1, 64, 0, stream>>>(bsum, bofs);
    scan_write_kernel<<<SCAN_GRID, SCAN_B, 0, stream>>>(cnt, bofs, off);
    scatter_kernel<<<N_EDGES / 256, 256, 0, stream>>>(grec, dst, off, slot, gdata);
    aggregate_project_kernel<<<N_NODES / 16, 256, 0, stream>>>(
        feat, W_sp, b_sp, off, gdata, (const short*)wnp, (const short*)wsp, bb, out);
}